// Round 1
// baseline (4247.529 us; speedup 1.0000x reference)
//
#include <hip/hip_runtime.h>

#define E_EDGES 320000
#define NF 20

__device__ __forceinline__ float selu_f(float x) {
    const float scale = 1.0507009873554805f;
    const float alpha = 1.6732632423543772f;
    return x > 0.f ? scale * x : scale * alpha * (__expf(x) - 1.f);
}

// B[e][o] = sum_f h[e][f] * W1[20+f][o] + b1[o]   (bottom half of msg_W1, bias folded)
__global__ void __launch_bounds__(256) kernel_B(
    const float* __restrict__ h, const float* __restrict__ W1,
    const float* __restrict__ b1, float* __restrict__ B)
{
    __shared__ float sw[640 + 32];
    for (int i = threadIdx.x; i < 640; i += 256) sw[i] = W1[640 + i];
    if (threadIdx.x < 32) sw[640 + threadIdx.x] = b1[threadIdx.x];
    __syncthreads();
    int e = blockIdx.x * 256 + threadIdx.x;
    float hv[NF];
    const float4* hp = reinterpret_cast<const float4*>(h + (size_t)e * NF);
    #pragma unroll
    for (int i = 0; i < 5; i++) {
        float4 v = hp[i];
        hv[4*i] = v.x; hv[4*i+1] = v.y; hv[4*i+2] = v.z; hv[4*i+3] = v.w;
    }
    float acc[32];
    #pragma unroll
    for (int o = 0; o < 32; o++) acc[o] = sw[640 + o];
    #pragma unroll
    for (int f = 0; f < NF; f++) {
        float hf = hv[f];
        #pragma unroll
        for (int o = 0; o < 32; o++) acc[o] += hf * sw[f*32 + o];
    }
    float4* Bp = reinterpret_cast<float4*>(B + (size_t)e * 32);
    #pragma unroll
    for (int i = 0; i < 8; i++) {
        float4 v; v.x = acc[4*i]; v.y = acc[4*i+1]; v.z = acc[4*i+2]; v.w = acc[4*i+3];
        Bp[i] = v;
    }
}

// One step: A on the fly, gather 16 contiguous B rows, selu-sum, @W2, GRU.
__global__ void __launch_bounds__(256) kernel_step(
    const float* __restrict__ h_in, float* __restrict__ h_out,
    const float* __restrict__ B, const int* __restrict__ dst,
    const float* __restrict__ W1, const float* __restrict__ W2, const float* __restrict__ b2,
    const float* __restrict__ Wih, const float* __restrict__ Whh,
    const float* __restrict__ bih, const float* __restrict__ bhh)
{
    __shared__ float sW1[640];   // top 20 rows of msg_W1
    __shared__ float sW2[640];   // (32,20)
    __shared__ float sb2[20];
    __shared__ float sWih[1200]; // (60,20)
    __shared__ float sWhh[1200];
    __shared__ float sbih[60];
    __shared__ float sbhh[60];
    for (int i = threadIdx.x; i < 640; i += 256) { sW1[i] = W1[i]; sW2[i] = W2[i]; }
    for (int i = threadIdx.x; i < 1200; i += 256) { sWih[i] = Wih[i]; sWhh[i] = Whh[i]; }
    if (threadIdx.x < 20) sb2[threadIdx.x] = b2[threadIdx.x];
    else if (threadIdx.x >= 64 && threadIdx.x < 124) sbih[threadIdx.x - 64] = bih[threadIdx.x - 64];
    else if (threadIdx.x >= 128 && threadIdx.x < 188) sbhh[threadIdx.x - 128] = bhh[threadIdx.x - 128];
    __syncthreads();

    int e = blockIdx.x * 256 + threadIdx.x;
    float hv[NF];
    const float4* hp = reinterpret_cast<const float4*>(h_in + (size_t)e * NF);
    #pragma unroll
    for (int i = 0; i < 5; i++) {
        float4 v = hp[i];
        hv[4*i] = v.x; hv[4*i+1] = v.y; hv[4*i+2] = v.z; hv[4*i+3] = v.w;
    }
    // A = h_e @ W1_top (bias lives in B)
    float A[32];
    #pragma unroll
    for (int o = 0; o < 32; o++) A[o] = 0.f;
    #pragma unroll
    for (int f = 0; f < NF; f++) {
        float hf = hv[f];
        #pragma unroll
        for (int o = 0; o < 32; o++) A[o] += hf * sW1[f*32 + o];
    }
    int d = dst[e];
    const float4* Bp = reinterpret_cast<const float4*>(B + (size_t)d * 16 * 32);
    float S[32];
    #pragma unroll
    for (int o = 0; o < 32; o++) S[o] = 0.f;
    #pragma unroll 2
    for (int k = 0; k < 16; k++) {
        float bj[32];
        const float4* p = Bp + k * 8;
        #pragma unroll
        for (int i = 0; i < 8; i++) {
            float4 v = p[i];
            bj[4*i] = v.x; bj[4*i+1] = v.y; bj[4*i+2] = v.z; bj[4*i+3] = v.w;
        }
        #pragma unroll
        for (int o = 0; o < 32; o++) S[o] += selu_f(A[o] + bj[o]);
    }
    // agg = S @ W2 + 16*b2
    float agg[NF];
    #pragma unroll
    for (int f = 0; f < NF; f++) agg[f] = 16.f * sb2[f];
    #pragma unroll
    for (int o = 0; o < 32; o++) {
        float s = S[o];
        #pragma unroll
        for (int f = 0; f < NF; f++) agg[f] += s * sW2[o*NF + f];
    }
    // GRU
    float hnew[NF];
    #pragma unroll
    for (int c = 0; c < NF; c++) {
        float ir = sbih[c],        hr = sbhh[c];
        float iz = sbih[20 + c],   hz = sbhh[20 + c];
        float in_ = sbih[40 + c],  hn = sbhh[40 + c];
        #pragma unroll
        for (int f = 0; f < NF; f++) {
            float a = agg[f], hh = hv[f];
            ir  += a  * sWih[c*NF + f];
            iz  += a  * sWih[(20 + c)*NF + f];
            in_ += a  * sWih[(40 + c)*NF + f];
            hr  += hh * sWhh[c*NF + f];
            hz  += hh * sWhh[(20 + c)*NF + f];
            hn  += hh * sWhh[(40 + c)*NF + f];
        }
        float r = 1.f / (1.f + __expf(-(ir + hr)));
        float z = 1.f / (1.f + __expf(-(iz + hz)));
        float xn = in_ + r * hn;
        xn = fminf(fmaxf(xn, -20.f), 20.f);
        float t = __expf(2.f * xn);
        float n = (t - 1.f) / (t + 1.f);
        hnew[c] = (1.f - z) * n + z * hv[c];
    }
    float4* op = reinterpret_cast<float4*>(h_out + (size_t)e * NF);
    #pragma unroll
    for (int i = 0; i < 5; i++) {
        float4 v; v.x = hnew[4*i]; v.y = hnew[4*i+1]; v.z = hnew[4*i+2]; v.w = hnew[4*i+3];
        op[i] = v;
    }
}

__global__ void __launch_bounds__(256) kernel_readout(
    const float* __restrict__ h,
    const float* __restrict__ W1, const float* __restrict__ b1,
    const float* __restrict__ W2, const float* __restrict__ b2,
    const float* __restrict__ W3, const float* __restrict__ b3,
    float* __restrict__ out)
{
    __shared__ float sW1[1280]; // (20,64)
    __shared__ float sb1[64];
    __shared__ float sW2[2048]; // (64,32)
    __shared__ float sb2[32];
    __shared__ float sW3[32];
    __shared__ float sb3;
    for (int i = threadIdx.x; i < 1280; i += 256) sW1[i] = W1[i];
    for (int i = threadIdx.x; i < 2048; i += 256) sW2[i] = W2[i];
    if (threadIdx.x < 64) sb1[threadIdx.x] = b1[threadIdx.x];
    else if (threadIdx.x >= 64 && threadIdx.x < 96) sb2[threadIdx.x - 64] = b2[threadIdx.x - 64];
    else if (threadIdx.x >= 96 && threadIdx.x < 128) sW3[threadIdx.x - 96] = W3[threadIdx.x - 96];
    if (threadIdx.x == 128) sb3 = b3[0];
    __syncthreads();

    int e = blockIdx.x * 256 + threadIdx.x;
    float hv[NF];
    const float4* hp = reinterpret_cast<const float4*>(h + (size_t)e * NF);
    #pragma unroll
    for (int i = 0; i < 5; i++) {
        float4 v = hp[i];
        hv[4*i] = v.x; hv[4*i+1] = v.y; hv[4*i+2] = v.z; hv[4*i+3] = v.w;
    }
    float x1[64];
    #pragma unroll
    for (int o = 0; o < 64; o++) x1[o] = sb1[o];
    #pragma unroll
    for (int f = 0; f < NF; f++) {
        float hf = hv[f];
        #pragma unroll
        for (int o = 0; o < 64; o++) x1[o] += hf * sW1[f*64 + o];
    }
    #pragma unroll
    for (int o = 0; o < 64; o++) x1[o] = selu_f(x1[o]);
    float x2[32];
    #pragma unroll
    for (int o = 0; o < 32; o++) x2[o] = sb2[o];
    #pragma unroll
    for (int i = 0; i < 64; i++) {
        float xi = x1[i];
        #pragma unroll
        for (int o = 0; o < 32; o++) x2[o] += xi * sW2[i*32 + o];
    }
    float acc = sb3;
    #pragma unroll
    for (int o = 0; o < 32; o++) acc += selu_f(x2[o]) * sW3[o];
    float sp = fmaxf(acc, 0.f) + log1pf(__expf(-fabsf(acc)));
    float w = sp + 0.1f;
    w = fminf(fmaxf(w, 0.1f), 10.f);
    out[e] = w;
}

extern "C" void kernel_launch(void* const* d_in, const int* in_sizes, int n_in,
                              void* d_out, int out_size, void* d_ws, size_t ws_size,
                              hipStream_t stream) {
    const float* edge_attr = (const float*)d_in[0];
    const float* msg_W1   = (const float*)d_in[1];
    const float* msg_b1   = (const float*)d_in[2];
    const float* msg_W2   = (const float*)d_in[3];
    const float* msg_b2   = (const float*)d_in[4];
    const float* gru_Wih  = (const float*)d_in[5];
    const float* gru_Whh  = (const float*)d_in[6];
    const float* gru_bih  = (const float*)d_in[7];
    const float* gru_bhh  = (const float*)d_in[8];
    const float* ro_W1    = (const float*)d_in[9];
    const float* ro_b1    = (const float*)d_in[10];
    const float* ro_W2    = (const float*)d_in[11];
    const float* ro_b2    = (const float*)d_in[12];
    const float* ro_W3    = (const float*)d_in[13];
    const float* ro_b3    = (const float*)d_in[14];
    const int* edge_index = (const int*)d_in[15];
    const int* dst = edge_index + E_EDGES;   // row 1 of (2,E)

    float* h_ws = (float*)d_ws;                       // E*20 floats
    float* Bt   = h_ws + (size_t)E_EDGES * NF;        // E*32 floats

    dim3 grid(E_EDGES / 256), block(256);
    const float* hin = edge_attr;
    for (int s = 0; s < 4; s++) {
        kernel_B<<<grid, block, 0, stream>>>(hin, msg_W1, msg_b1, Bt);
        kernel_step<<<grid, block, 0, stream>>>(hin, h_ws, Bt, dst,
            msg_W1, msg_W2, msg_b2, gru_Wih, gru_Whh, gru_bih, gru_bhh);
        hin = h_ws;
    }
    kernel_readout<<<grid, block, 0, stream>>>(h_ws, ro_W1, ro_b1, ro_W2, ro_b2,
                                               ro_W3, ro_b3, (float*)d_out);
}